// Round 8
// baseline (133.990 us; speedup 1.0000x reference)
//
#include <hip/hip_runtime.h>

#define NN 8192
#define KK 512
#define INVT 14.285714285714286f   /* 1/0.07 */
#define K2E 20.60992915555662f     /* (1/0.07) * log2(e) */
#define EPSF 1e-6f

#define NB 64                      /* 8192/128 tile-blocks per dim */
#define NTRI (NB * (NB + 1) / 2)   /* 2080 upper-triangle tiles */

typedef short bf16x8 __attribute__((ext_vector_type(8)));
typedef float f32x4 __attribute__((ext_vector_type(4)));

__device__ __forceinline__ unsigned short f2bf(float f) {
  unsigned int u = __float_as_uint(f);
  u = u + 0x7FFFu + ((u >> 16) & 1u);
  return (unsigned short)(u >> 16);
}

__device__ __forceinline__ void load_lds16(const void* g, void* l) {
  __builtin_amdgcn_global_load_lds(
      (const __attribute__((address_space(1))) unsigned int*)g,
      (__attribute__((address_space(3))) unsigned int*)l, 16, 0, 0);
}

// Kernel 1: fp32 -> bf16 conversion of features + per-class counts.
__global__ void prep_kernel(const float* __restrict__ feats,
                            const int* __restrict__ labels,
                            unsigned short* __restrict__ fb,
                            int* __restrict__ cnt) {
  int tid = blockIdx.x * 256 + threadIdx.x;  // 524288 threads, 8 elems each
  const float4* src = (const float4*)feats + (size_t)tid * 2;
  float4 a = src[0];
  float4 b = src[1];
  bf16x8 o;
  o[0] = (short)f2bf(a.x); o[1] = (short)f2bf(a.y);
  o[2] = (short)f2bf(a.z); o[3] = (short)f2bf(a.w);
  o[4] = (short)f2bf(b.x); o[5] = (short)f2bf(b.y);
  o[6] = (short)f2bf(b.z); o[7] = (short)f2bf(b.w);
  *(bf16x8*)(fb + (size_t)tid * 8) = o;
  if (tid < NN) atomicAdd(&cnt[labels[tid]], 1);
}

// Kernel 2: SYMMETRIC fused GEMM, upper-triangle 128x128 tiles (2080 blocks).
// Off-diagonal tiles contribute row-sums AND column-sums (e_ij and the label
// mask are symmetric). NO atomics: block (rb,cb) writes row-partials to
// part[cb][rb-range], col-partials to part[rb][cb-range]; every cell of
// part[64][8192] has exactly one writer. Col-partials are accumulated in
// REGISTERS across the main loop (round-7 bug: 4 waves plain-stored the same
// address), cross-wave reduced through LDS once at the end.
__global__ __launch_bounds__(256, 2) void
scl_main_kernel(const unsigned short* __restrict__ fb,
                const int* __restrict__ labels,
                float* __restrict__ Spart, float* __restrict__ Ppart) {
  __shared__ unsigned short lds[64 * KK];  // 64 KB, [col][k], XOR-swizzled

  // Decode linear bid -> (rb, cb) with rb <= cb over the 64x64 tile grid.
  int rb = 0, rem = blockIdx.x;
  while (rem >= NB - rb) { rem -= NB - rb; ++rb; }
  const int cb = rb + rem;
  const bool diag = (rb == cb);

  const int tid = threadIdx.x;
  const int w = tid >> 6;
  const int l = tid & 63;
  const int lo = l & 15;  // A-row / B-col / C-col lane index
  const int g = l >> 4;   // k-group (operands) / row-group (C)

  const int row0 = rb * 128 + w * 32;
  const int colBase = cb * 128;
  const int myrow0 = row0 + g * 4;        // frag0 C rows
  const int myrow1 = row0 + 16 + g * 4;   // frag1 C rows

  // A fragments in registers: frag f row = row0 + f*16 + lo, k = ks*32 + g*8..+7
  bf16x8 Af0[16], Af1[16];
  {
    const unsigned short* a0 = fb + (size_t)(row0 + lo) * KK;
    const unsigned short* a1 = fb + (size_t)(row0 + 16 + lo) * KK;
#pragma unroll
    for (int ks = 0; ks < 16; ++ks) {
      Af0[ks] = *(const bf16x8*)(a0 + ks * 32 + g * 8);
      Af1[ks] = *(const bf16x8*)(a1 + ks * 32 + g * 8);
    }
  }

  int labr0[4], labr1[4];
#pragma unroll
  for (int r = 0; r < 4; ++r) {
    labr0[r] = labels[myrow0 + r];
    labr1[r] = labels[myrow1 + r];
  }
  // All 8 per-lane column labels hoisted (no global loads in hot loop).
  int labc[2][4];
#pragma unroll
  for (int h = 0; h < 2; ++h)
#pragma unroll
    for (int st = 0; st < 4; ++st)
      labc[h][st] = labels[colBase + h * 64 + st * 16 + lo];

  f32x4 Sac0 = {0.f,0.f,0.f,0.f}, Sac1 = {0.f,0.f,0.f,0.f};
  f32x4 Pac0 = {0.f,0.f,0.f,0.f}, Pac1 = {0.f,0.f,0.f,0.f};
  // Column-side register accumulators: slot (h,st) = this lane's column
  // colBase + h*64 + st*16 + lo, summed over this wave's 8 C-rows (per g).
  float ceA[2][4] = {{0.f,0.f,0.f,0.f},{0.f,0.f,0.f,0.f}};
  float cpA[2][4] = {{0.f,0.f,0.f,0.f},{0.f,0.f,0.f,0.f}};

#pragma unroll
  for (int h = 0; h < 2; ++h) {
    const int colb = colBase + h * 64;
    __syncthreads();  // previous half fully consumed
    // Stage 64 cols x 1KB; wave w stages cols w*16..w*16+15. LDS dest linear;
    // global source inverse-XOR-swizzled (proven round-3 pattern).
#pragma unroll
    for (int j = 0; j < 16; ++j) {
      const int col = w * 16 + j;  // wave-uniform
      const int kc = (l & 56) | ((l ^ col) & 7);
      const unsigned short* src = fb + (size_t)(colb + col) * KK + kc * 8;
      load_lds16((const void*)src, (void*)&lds[col * KK]);
    }
    __syncthreads();  // compiler drains vmcnt before barrier

#pragma unroll
    for (int st = 0; st < 4; ++st) {
      const int ct = st * 16 + lo;        // col within LDS tile
      const int colg = colb + ct;         // global col
      const int lc = labc[h][st];
      f32x4 a0 = {0.f,0.f,0.f,0.f};
      f32x4 a1 = {0.f,0.f,0.f,0.f};
#pragma unroll
      for (int ks = 0; ks < 16; ++ks) {
        const int kc = ks * 4 + g;
        const int phys = (kc & 56) | ((kc ^ ct) & 7);
        bf16x8 Bf = *(const bf16x8*)(&lds[ct * KK + phys * 8]);
        a0 = __builtin_amdgcn_mfma_f32_16x16x32_bf16(Af0[ks], Bf, a0, 0, 0, 0);
        a1 = __builtin_amdgcn_mfma_f32_16x16x32_bf16(Af1[ks], Bf, a1, 0, 0, 0);
      }
#pragma unroll
      for (int r = 0; r < 4; ++r) {
        const float s0 = a0[r];
        const float e0 = __builtin_amdgcn_exp2f(__builtin_fmaf(s0, K2E, -K2E));
        Sac0[r] += e0;
        ceA[h][st] += e0;
        if (lc == labr0[r]) { Pac0[r] += s0; cpA[h][st] += s0; }
        const float s1 = a1[r];
        const float e1 = __builtin_amdgcn_exp2f(__builtin_fmaf(s1, K2E, -K2E));
        Sac1[r] += e1;
        ceA[h][st] += e1;
        if (lc == labr1[r]) { Pac1[r] += s1; cpA[h][st] += s1; }
        if (diag) {  // self term always label-matches; row-side only
          if (colg == myrow0 + r) { Sac0[r] -= e0; Pac0[r] -= s0; }
          if (colg == myrow1 + r) { Sac1[r] -= e1; Pac1[r] -= s1; }
        }
      }
    }
  }

  // Row-side: reduce across the 16 lanes sharing a row set; plain store into
  // partial slab cb (unique writer for cell [cb][row]).
#pragma unroll
  for (int r = 0; r < 4; ++r) {
    float s0 = Sac0[r], p0 = Pac0[r], s1 = Sac1[r], p1 = Pac1[r];
#pragma unroll
    for (int m = 1; m < 16; m <<= 1) {
      s0 += __shfl_xor(s0, m, 64);
      p0 += __shfl_xor(p0, m, 64);
      s1 += __shfl_xor(s1, m, 64);
      p1 += __shfl_xor(p1, m, 64);
    }
    if (lo == 0) {
      Spart[cb * NN + myrow0 + r] = s0;
      Ppart[cb * NN + myrow0 + r] = p0;
      Spart[cb * NN + myrow1 + r] = s1;
      Ppart[cb * NN + myrow1 + r] = p1;
    }
  }

  // Col-side: cross-g shfl reduce (wave's 32 rows), stage per-wave sums in
  // LDS (B tiles fully consumed), sum the 4 waves, one plain store per column
  // into slab rb (unique writer for cell [rb][col], rb < cb).
  if (!diag) {
    __syncthreads();  // all waves done with B-tile reads; lds reusable
    float* redS = (float*)lds;   // [4 waves][8 slots][16 lanes]
    float* redP = redS + 512;
#pragma unroll
    for (int h = 0; h < 2; ++h) {
#pragma unroll
      for (int st = 0; st < 4; ++st) {
        float ce = ceA[h][st], cp = cpA[h][st];
        ce += __shfl_xor(ce, 16, 64);
        ce += __shfl_xor(ce, 32, 64);
        cp += __shfl_xor(cp, 16, 64);
        cp += __shfl_xor(cp, 32, 64);
        if (l < 16) {
          redS[(w * 8 + h * 4 + st) * 16 + lo] = ce;
          redP[(w * 8 + h * 4 + st) * 16 + lo] = cp;
        }
      }
    }
    __syncthreads();
    if (tid < 128) {  // slot = tid>>4 (h=slot>>2, st=slot&3), lane = tid&15
      const int slot = tid >> 4, ln = tid & 15;
      float S = redS[slot * 16 + ln] + redS[(8 + slot) * 16 + ln] +
                redS[(16 + slot) * 16 + ln] + redS[(24 + slot) * 16 + ln];
      float P = redP[slot * 16 + ln] + redP[(8 + slot) * 16 + ln] +
                redP[(16 + slot) * 16 + ln] + redP[(24 + slot) * 16 + ln];
      const int colg = colBase + (slot >> 2) * 64 + (slot & 3) * 16 + ln;
      Spart[rb * NN + colg] = S;
      Ppart[rb * NN + colg] = P;
    }
  }
}

// Kernel 3: gather the 64 partials per row (coalesced), per-row loss, mean.
__global__ void finish_kernel(const float* __restrict__ Spart,
                              const float* __restrict__ Ppart,
                              const int* __restrict__ labels,
                              const int* __restrict__ cnt,
                              float* __restrict__ out) {
  int i = blockIdx.x * 256 + threadIdx.x;  // 8192 threads
  float S = 0.f, P = 0.f;
#pragma unroll 8
  for (int p = 0; p < NB; ++p) {
    S += Spart[p * NN + i];
    P += Ppart[p * NN + i];
  }
  float C = (float)(cnt[labels[i]] - 1);
  float lp = P * INVT - C * (INVT + logf(S + EPSF));
  float v = lp / (C + EPSF);
#pragma unroll
  for (int m = 1; m < 64; m <<= 1) v += __shfl_xor(v, m, 64);
  if ((threadIdx.x & 63) == 0) atomicAdd(out, -v * (1.0f / NN));
}

extern "C" void kernel_launch(void* const* d_in, const int* in_sizes, int n_in,
                              void* d_out, int out_size, void* d_ws, size_t ws_size,
                              hipStream_t stream) {
  const float* feats = (const float*)d_in[0];
  const int* labels = (const int*)d_in[1];

  // ws layout: [0,8MB) bf16 feats; [8,10MB) Spart[64][8192]; [10,12MB) Ppart;
  // then cnt (128 i32). Spart/Ppart need no init (every cell written once).
  unsigned short* fb = (unsigned short*)d_ws;
  const size_t FB_BYTES = (size_t)NN * KK * 2;  // 8388608
  float* Spart = (float*)((char*)d_ws + FB_BYTES);
  float* Ppart = Spart + (size_t)NB * NN;
  int* cnt = (int*)(Ppart + (size_t)NB * NN);

  hipMemsetAsync(cnt, 0, 512, stream);
  hipMemsetAsync(d_out, 0, sizeof(float), stream);

  prep_kernel<<<dim3((NN * KK / 8) / 256), dim3(256), 0, stream>>>(feats, labels, fb, cnt);
  scl_main_kernel<<<dim3(NTRI), dim3(256), 0, stream>>>(fb, labels, Spart, Ppart);
  finish_kernel<<<dim3(NN / 256), dim3(256), 0, stream>>>(Spart, Ppart, labels, cnt, (float*)d_out);
}

// Round 9
// 131.617 us; speedup vs baseline: 1.0180x; 1.0180x over previous
//
#include <hip/hip_runtime.h>

#define NN 8192
#define KK 512
#define INVT 14.285714285714286f   /* 1/0.07 */
#define K2E 20.60992915555662f     /* (1/0.07) * log2(e) */
#define EPSF 1e-6f

#define NB 64                      /* 8192/128 tile-blocks per dim */
#define NTRI (NB * (NB + 1) / 2)   /* 2080 upper-triangle tiles = 8*260 */

typedef short bf16x8 __attribute__((ext_vector_type(8)));
typedef float f32x4 __attribute__((ext_vector_type(4)));

__device__ __forceinline__ unsigned short f2bf(float f) {
  unsigned int u = __float_as_uint(f);
  u = u + 0x7FFFu + ((u >> 16) & 1u);
  return (unsigned short)(u >> 16);
}

__device__ __forceinline__ void load_lds16(const void* g, void* l) {
  __builtin_amdgcn_global_load_lds(
      (const __attribute__((address_space(1))) unsigned int*)g,
      (__attribute__((address_space(3))) unsigned int*)l, 16, 0, 0);
}

// Kernel 1: fp32 -> bf16 conversion of features + per-class counts.
__global__ void prep_kernel(const float* __restrict__ feats,
                            const int* __restrict__ labels,
                            unsigned short* __restrict__ fb,
                            int* __restrict__ cnt) {
  int tid = blockIdx.x * 256 + threadIdx.x;  // 524288 threads, 8 elems each
  const float4* src = (const float4*)feats + (size_t)tid * 2;
  float4 a = src[0];
  float4 b = src[1];
  bf16x8 o;
  o[0] = (short)f2bf(a.x); o[1] = (short)f2bf(a.y);
  o[2] = (short)f2bf(a.z); o[3] = (short)f2bf(a.w);
  o[4] = (short)f2bf(b.x); o[5] = (short)f2bf(b.y);
  o[6] = (short)f2bf(b.z); o[7] = (short)f2bf(b.w);
  *(bf16x8*)(fb + (size_t)tid * 8) = o;
  if (tid < NN) atomicAdd(&cnt[labels[tid]], 1);
}

// Kernel 2: SYMMETRIC fused GEMM, upper-triangle 128x128 tiles (2080 blocks).
// Round-9 changes vs round-8 (same geometry, same inner loop):
//  (a) row-side partials staged in LDS then stored as 512B coalesced bursts
//      (round-8: 4-sparse-lane stores -> 62MB write amplification);
//  (b) balanced XCD stripe mapping: XCD x (=bid%8) owns column-stripes x and
//      15-x (260 tiles each) -> every B-panel is XCD-exclusive/L2-resident;
//  (c) h=0 B-stage issued before A-register loads (overlapped in flight).
__global__ __launch_bounds__(256, 2) void
scl_main_kernel(const unsigned short* __restrict__ fb,
                const int* __restrict__ labels,
                float* __restrict__ Spart, float* __restrict__ Ppart) {
  __shared__ unsigned short lds[64 * KK];  // 64 KB, [col][k], XOR-swizzled

  // Balanced stripe decode: XCD x gets stripes {x, 15-x}; stripe s covers
  // cb in [4s, 4s+4), each cb has cb+1 tiles (rb = 0..cb).
  const int x = blockIdx.x & 7;
  int mm = blockIdx.x >> 3;  // 0..259
  const int T1 = 16 * x + 10;
  int s = x;
  if (mm >= T1) { s = 15 - x; mm -= T1; }
  const int base = 4 * s;
  const int w0 = base + 1, w1 = base + 2, w2 = base + 3;
  int cb, rb;
  if (mm < w0)                { cb = base;     rb = mm; }
  else if (mm < w0 + w1)      { cb = base + 1; rb = mm - w0; }
  else if (mm < w0 + w1 + w2) { cb = base + 2; rb = mm - w0 - w1; }
  else                        { cb = base + 3; rb = mm - w0 - w1 - w2; }
  const bool diag = (rb == cb);

  const int tid = threadIdx.x;
  const int w = tid >> 6;
  const int l = tid & 63;
  const int lo = l & 15;  // A-row / B-col / C-col lane index
  const int g = l >> 4;   // k-group (operands) / row-group (C)

  const int row0 = rb * 128 + w * 32;
  const int colBase = cb * 128;
  const int myrow0 = row0 + g * 4;        // frag0 C rows
  const int myrow1 = row0 + 16 + g * 4;   // frag1 C rows

// Stage 64 cols x 1KB; wave w stages cols w*16..w*16+15. LDS dest linear;
// global source inverse-XOR-swizzled (proven pattern, ~2-way-free reads).
#define STAGE(colb)                                                            \
  {                                                                            \
    _Pragma("unroll") for (int j = 0; j < 16; ++j) {                           \
      const int col = w * 16 + j; /* wave-uniform */                           \
      const int kc = (l & 56) | ((l ^ col) & 7);                               \
      const unsigned short* src = fb + (size_t)((colb) + col) * KK + kc * 8;   \
      load_lds16((const void*)src, (void*)&lds[col * KK]);                     \
    }                                                                          \
  }

  // (c) issue h=0 staging first; A-frag loads fly concurrently.
  STAGE(colBase);

  // A fragments in registers: frag f row = row0 + f*16 + lo, k = ks*32 + g*8..+7
  bf16x8 Af0[16], Af1[16];
  {
    const unsigned short* a0 = fb + (size_t)(row0 + lo) * KK;
    const unsigned short* a1 = fb + (size_t)(row0 + 16 + lo) * KK;
#pragma unroll
    for (int ks = 0; ks < 16; ++ks) {
      Af0[ks] = *(const bf16x8*)(a0 + ks * 32 + g * 8);
      Af1[ks] = *(const bf16x8*)(a1 + ks * 32 + g * 8);
    }
  }

  int labr0[4], labr1[4];
#pragma unroll
  for (int r = 0; r < 4; ++r) {
    labr0[r] = labels[myrow0 + r];
    labr1[r] = labels[myrow1 + r];
  }
  int labc[2][4];
#pragma unroll
  for (int h = 0; h < 2; ++h)
#pragma unroll
    for (int st = 0; st < 4; ++st)
      labc[h][st] = labels[colBase + h * 64 + st * 16 + lo];

  f32x4 Sac0 = {0.f,0.f,0.f,0.f}, Sac1 = {0.f,0.f,0.f,0.f};
  f32x4 Pac0 = {0.f,0.f,0.f,0.f}, Pac1 = {0.f,0.f,0.f,0.f};
  float ceA[2][4] = {{0.f,0.f,0.f,0.f},{0.f,0.f,0.f,0.f}};
  float cpA[2][4] = {{0.f,0.f,0.f,0.f},{0.f,0.f,0.f,0.f}};

  __syncthreads();  // h=0 staged (vmcnt drained), A-frags also landed

#pragma unroll
  for (int h = 0; h < 2; ++h) {
    const int colb = colBase + h * 64;

#pragma unroll
    for (int st = 0; st < 4; ++st) {
      const int ct = st * 16 + lo;        // col within LDS tile
      const int colg = colb + ct;         // global col
      const int lc = labc[h][st];
      f32x4 a0 = {0.f,0.f,0.f,0.f};
      f32x4 a1 = {0.f,0.f,0.f,0.f};
#pragma unroll
      for (int ks = 0; ks < 16; ++ks) {
        const int kc = ks * 4 + g;
        const int phys = (kc & 56) | ((kc ^ ct) & 7);
        bf16x8 Bf = *(const bf16x8*)(&lds[ct * KK + phys * 8]);
        a0 = __builtin_amdgcn_mfma_f32_16x16x32_bf16(Af0[ks], Bf, a0, 0, 0, 0);
        a1 = __builtin_amdgcn_mfma_f32_16x16x32_bf16(Af1[ks], Bf, a1, 0, 0, 0);
      }
#pragma unroll
      for (int r = 0; r < 4; ++r) {
        const float s0 = a0[r];
        const float e0 = __builtin_amdgcn_exp2f(__builtin_fmaf(s0, K2E, -K2E));
        Sac0[r] += e0;
        ceA[h][st] += e0;
        if (lc == labr0[r]) { Pac0[r] += s0; cpA[h][st] += s0; }
        const float s1 = a1[r];
        const float e1 = __builtin_amdgcn_exp2f(__builtin_fmaf(s1, K2E, -K2E));
        Sac1[r] += e1;
        ceA[h][st] += e1;
        if (lc == labr1[r]) { Pac1[r] += s1; cpA[h][st] += s1; }
        if (diag) {  // self term always label-matches; row-side only
          if (colg == myrow0 + r) { Sac0[r] -= e0; Pac0[r] -= s0; }
          if (colg == myrow1 + r) { Sac1[r] -= e1; Pac1[r] -= s1; }
        }
      }
    }
    if (h == 0) {
      __syncthreads();      // all waves done reading h=0 tile
      STAGE(colBase + 64);  // stage h=1
      __syncthreads();      // drained + visible
    }
  }

  // ---- Epilogue: all partials staged in LDS, stored as coalesced bursts ----
  __syncthreads();  // B-tile reads complete; lds reusable
  float* redS = (float*)lds;        // [4 waves][8 slots][16 lanes] col partials
  float* redP = redS + 512;
  float* SrowL = redP + 512;        // [128] block-final row partials
  float* ProwL = SrowL + 128;

  // Row side: rows are wave-exclusive; 16-lane shfl tree -> block-final.
#pragma unroll
  for (int r = 0; r < 4; ++r) {
    float s0 = Sac0[r], p0 = Pac0[r], s1 = Sac1[r], p1 = Pac1[r];
#pragma unroll
    for (int m = 1; m < 16; m <<= 1) {
      s0 += __shfl_xor(s0, m, 64);
      p0 += __shfl_xor(p0, m, 64);
      s1 += __shfl_xor(s1, m, 64);
      p1 += __shfl_xor(p1, m, 64);
    }
    if (lo == 0) {
      const int rl = w * 32 + g * 4 + r;  // local row (myrow - rb*128)
      SrowL[rl] = s0;      ProwL[rl] = p0;
      SrowL[rl + 16] = s1; ProwL[rl + 16] = p1;
    }
  }

  // Col side: cross-g shfl, stage per-wave sums (only off-diag blocks store).
  if (!diag) {
#pragma unroll
    for (int h = 0; h < 2; ++h) {
#pragma unroll
      for (int st = 0; st < 4; ++st) {
        float ce = ceA[h][st], cp = cpA[h][st];
        ce += __shfl_xor(ce, 16, 64);
        ce += __shfl_xor(ce, 32, 64);
        cp += __shfl_xor(cp, 16, 64);
        cp += __shfl_xor(cp, 32, 64);
        if (l < 16) {
          redS[(w * 8 + h * 4 + st) * 16 + lo] = ce;
          redP[(w * 8 + h * 4 + st) * 16 + lo] = cp;
        }
      }
    }
  }
  __syncthreads();

  if (tid < 128) {
    // Row partials -> slab cb, contiguous 512B per array.
    Spart[cb * NN + rb * 128 + tid] = SrowL[tid];
    Ppart[cb * NN + rb * 128 + tid] = ProwL[tid];
    if (!diag) {
      // Col partials -> slab rb; col index == tid (h=tid>>6, st=(tid>>4)&3).
      const int slot = tid >> 4, ln = tid & 15;
      float S = redS[slot * 16 + ln] + redS[(8 + slot) * 16 + ln] +
                redS[(16 + slot) * 16 + ln] + redS[(24 + slot) * 16 + ln];
      float P = redP[slot * 16 + ln] + redP[(8 + slot) * 16 + ln] +
                redP[(16 + slot) * 16 + ln] + redP[(24 + slot) * 16 + ln];
      Spart[rb * NN + colBase + tid] = S;
      Ppart[rb * NN + colBase + tid] = P;
    }
  }
#undef STAGE
}

// Kernel 3: gather the 64 partials per row (coalesced), per-row loss, mean.
__global__ void finish_kernel(const float* __restrict__ Spart,
                              const float* __restrict__ Ppart,
                              const int* __restrict__ labels,
                              const int* __restrict__ cnt,
                              float* __restrict__ out) {
  int i = blockIdx.x * 256 + threadIdx.x;  // 8192 threads
  float S = 0.f, P = 0.f;
#pragma unroll 8
  for (int p = 0; p < NB; ++p) {
    S += Spart[p * NN + i];
    P += Ppart[p * NN + i];
  }
  float C = (float)(cnt[labels[i]] - 1);
  float lp = P * INVT - C * (INVT + logf(S + EPSF));
  float v = lp / (C + EPSF);
#pragma unroll
  for (int m = 1; m < 64; m <<= 1) v += __shfl_xor(v, m, 64);
  if ((threadIdx.x & 63) == 0) atomicAdd(out, -v * (1.0f / NN));
}

extern "C" void kernel_launch(void* const* d_in, const int* in_sizes, int n_in,
                              void* d_out, int out_size, void* d_ws, size_t ws_size,
                              hipStream_t stream) {
  const float* feats = (const float*)d_in[0];
  const int* labels = (const int*)d_in[1];

  // ws layout: [0,8MB) bf16 feats; [8,10MB) Spart[64][8192]; [10,12MB) Ppart;
  // then cnt (128 i32). Spart/Ppart need no init (every cell written once).
  unsigned short* fb = (unsigned short*)d_ws;
  const size_t FB_BYTES = (size_t)NN * KK * 2;  // 8388608
  float* Spart = (float*)((char*)d_ws + FB_BYTES);
  float* Ppart = Spart + (size_t)NB * NN;
  int* cnt = (int*)(Ppart + (size_t)NB * NN);

  hipMemsetAsync(cnt, 0, 512, stream);
  hipMemsetAsync(d_out, 0, sizeof(float), stream);

  prep_kernel<<<dim3((NN * KK / 8) / 256), dim3(256), 0, stream>>>(feats, labels, fb, cnt);
  scl_main_kernel<<<dim3(NTRI), dim3(256), 0, stream>>>(fb, labels, Spart, Ppart);
  finish_kernel<<<dim3(NN / 256), dim3(256), 0, stream>>>(Spart, Ppart, labels, cnt, (float*)d_out);
}

// Round 10
// 106.418 us; speedup vs baseline: 1.2591x; 1.2368x over previous
//
#include <hip/hip_runtime.h>

#define NN 8192
#define KK 512
#define INVT 14.285714285714286f   /* 1/0.07 */
#define K2E 20.60992915555662f     /* (1/0.07) * log2(e) */
#define EPSF 1e-6f

#define NB 64                      /* 8192/128 tile-blocks per dim */
#define NTRI (NB * (NB + 1) / 2)   /* 2080 upper-triangle tiles = 8*260 */

typedef short bf16x8 __attribute__((ext_vector_type(8)));
typedef float f32x4 __attribute__((ext_vector_type(4)));

__device__ __forceinline__ unsigned short f2bf(float f) {
  unsigned int u = __float_as_uint(f);
  u = u + 0x7FFFu + ((u >> 16) & 1u);
  return (unsigned short)(u >> 16);
}

__device__ __forceinline__ void load_lds16(const void* g, void* l) {
  __builtin_amdgcn_global_load_lds(
      (const __attribute__((address_space(1))) unsigned int*)g,
      (__attribute__((address_space(3))) unsigned int*)l, 16, 0, 0);
}

// Kernel 1: fp32 -> bf16 conversion of features + per-class counts.
__global__ void prep_kernel(const float* __restrict__ feats,
                            const int* __restrict__ labels,
                            unsigned short* __restrict__ fb,
                            int* __restrict__ cnt) {
  int tid = blockIdx.x * 256 + threadIdx.x;  // 524288 threads, 8 elems each
  const float4* src = (const float4*)feats + (size_t)tid * 2;
  float4 a = src[0];
  float4 b = src[1];
  bf16x8 o;
  o[0] = (short)f2bf(a.x); o[1] = (short)f2bf(a.y);
  o[2] = (short)f2bf(a.z); o[3] = (short)f2bf(a.w);
  o[4] = (short)f2bf(b.x); o[5] = (short)f2bf(b.y);
  o[6] = (short)f2bf(b.z); o[7] = (short)f2bf(b.w);
  *(bf16x8*)(fb + (size_t)tid * 8) = o;
  if (tid < NN) atomicAdd(&cnt[labels[tid]], 1);
}

// Kernel 2: SYMMETRIC fused GEMM, upper-triangle 128x128 tiles (2080 blocks).
// Round-10 change vs round-9: column-side partial accumulators moved from
// REGISTERS (ceA/cpA[2][4] -> pushed past the ~256 VGPR/wave budget at
// launch_bounds(256,2) -> scratch spill, 73MB WRITE_SIZE, RMW'd every
// window) into a 4KB LDS side-buffer with wave-exclusive slices. Inner GEMM
// loop unchanged (A in regs, 64-col x 1KB XOR-swizzled B tiles).
__global__ __launch_bounds__(256, 2) void
scl_main_kernel(const unsigned short* __restrict__ fb,
                const int* __restrict__ labels,
                float* __restrict__ Spart, float* __restrict__ Ppart) {
  __shared__ unsigned short lds[64 * KK];        // 64 KB B tile, XOR-swizzled
  __shared__ float colS[4][128], colP[4][128];   // 4 KB col partials per wave
  __shared__ float SrowL[128], ProwL[128];       // 1 KB block row partials

  // Balanced stripe decode: XCD x (=bid%8) gets stripes {x, 15-x}; stripe s
  // covers cb in [4s, 4s+4), each cb has cb+1 tiles (rb = 0..cb).
  const int x = blockIdx.x & 7;
  int mm = blockIdx.x >> 3;  // 0..259
  const int T1 = 16 * x + 10;
  int s = x;
  if (mm >= T1) { s = 15 - x; mm -= T1; }
  const int base = 4 * s;
  const int w0 = base + 1, w1 = base + 2, w2 = base + 3;
  int cb, rb;
  if (mm < w0)                { cb = base;     rb = mm; }
  else if (mm < w0 + w1)      { cb = base + 1; rb = mm - w0; }
  else if (mm < w0 + w1 + w2) { cb = base + 2; rb = mm - w0 - w1; }
  else                        { cb = base + 3; rb = mm - w0 - w1 - w2; }
  const bool diag = (rb == cb);

  const int tid = threadIdx.x;
  const int w = tid >> 6;
  const int l = tid & 63;
  const int lo = l & 15;  // A-row / B-col / C-col lane index
  const int g = l >> 4;   // k-group (operands) / row-group (C)

  const int row0 = rb * 128 + w * 32;
  const int colBase = cb * 128;
  const int myrow0 = row0 + g * 4;        // frag0 C rows
  const int myrow1 = row0 + 16 + g * 4;   // frag1 C rows

// Stage 64 cols x 1KB; wave w stages cols w*16..w*16+15. LDS dest linear;
// global source inverse-XOR-swizzled (proven pattern, ~2-way-free reads).
#define STAGE(colb)                                                            \
  {                                                                            \
    _Pragma("unroll") for (int j = 0; j < 16; ++j) {                           \
      const int col = w * 16 + j; /* wave-uniform */                           \
      const int kc = (l & 56) | ((l ^ col) & 7);                               \
      const unsigned short* src = fb + (size_t)((colb) + col) * KK + kc * 8;   \
      load_lds16((const void*)src, (void*)&lds[col * KK]);                     \
    }                                                                          \
  }

  // Issue h=0 staging first; A-frag loads fly concurrently.
  STAGE(colBase);

  // Zero this wave's col-partial slice (wave-exclusive; no barrier needed).
  colS[w][l] = 0.f;      colP[w][l] = 0.f;
  colS[w][l + 64] = 0.f; colP[w][l + 64] = 0.f;

  // A fragments in registers: frag f row = row0 + f*16 + lo, k = ks*32 + g*8..+7
  bf16x8 Af0[16], Af1[16];
  {
    const unsigned short* a0 = fb + (size_t)(row0 + lo) * KK;
    const unsigned short* a1 = fb + (size_t)(row0 + 16 + lo) * KK;
#pragma unroll
    for (int ks = 0; ks < 16; ++ks) {
      Af0[ks] = *(const bf16x8*)(a0 + ks * 32 + g * 8);
      Af1[ks] = *(const bf16x8*)(a1 + ks * 32 + g * 8);
    }
  }

  int labr0[4], labr1[4];
#pragma unroll
  for (int r = 0; r < 4; ++r) {
    labr0[r] = labels[myrow0 + r];
    labr1[r] = labels[myrow1 + r];
  }

  f32x4 Sac0 = {0.f,0.f,0.f,0.f}, Sac1 = {0.f,0.f,0.f,0.f};
  f32x4 Pac0 = {0.f,0.f,0.f,0.f}, Pac1 = {0.f,0.f,0.f,0.f};

  __syncthreads();  // h=0 staged (vmcnt drained), A-frags also landed

#pragma unroll
  for (int h = 0; h < 2; ++h) {
    const int colb = colBase + h * 64;
    // Per-half column labels (L2-hot, 4 regs instead of 8 live the whole loop).
    int labc[4];
#pragma unroll
    for (int st = 0; st < 4; ++st) labc[st] = labels[colb + st * 16 + lo];

#pragma unroll
    for (int st = 0; st < 4; ++st) {
      const int ct = st * 16 + lo;        // col within LDS tile
      const int colg = colb + ct;         // global col
      const int lc = labc[st];
      f32x4 a0 = {0.f,0.f,0.f,0.f};
      f32x4 a1 = {0.f,0.f,0.f,0.f};
#pragma unroll
      for (int ks = 0; ks < 16; ++ks) {
        const int kc = ks * 4 + g;
        const int phys = (kc & 56) | ((kc ^ ct) & 7);
        bf16x8 Bf = *(const bf16x8*)(&lds[ct * KK + phys * 8]);
        a0 = __builtin_amdgcn_mfma_f32_16x16x32_bf16(Af0[ks], Bf, a0, 0, 0, 0);
        a1 = __builtin_amdgcn_mfma_f32_16x16x32_bf16(Af1[ks], Bf, a1, 0, 0, 0);
      }
      float ce = 0.f, cp = 0.f;  // this window's col partial (short-lived)
#pragma unroll
      for (int r = 0; r < 4; ++r) {
        const float s0 = a0[r];
        const float e0 = __builtin_amdgcn_exp2f(__builtin_fmaf(s0, K2E, -K2E));
        Sac0[r] += e0;
        ce += e0;
        if (lc == labr0[r]) { Pac0[r] += s0; cp += s0; }
        const float s1 = a1[r];
        const float e1 = __builtin_amdgcn_exp2f(__builtin_fmaf(s1, K2E, -K2E));
        Sac1[r] += e1;
        ce += e1;
        if (lc == labr1[r]) { Pac1[r] += s1; cp += s1; }
        if (diag) {  // self term always label-matches; row-side only
          if (colg == myrow0 + r) { Sac0[r] -= e0; Pac0[r] -= s0; }
          if (colg == myrow1 + r) { Sac1[r] -= e1; Pac1[r] -= s1; }
        }
      }
      if (!diag) {
        // Cross-g reduce (wave's 32 rows) then accumulate into the wave's
        // LDS col-partial slice (RMW, wave-exclusive, conflict-free).
        ce += __shfl_xor(ce, 16, 64);
        ce += __shfl_xor(ce, 32, 64);
        cp += __shfl_xor(cp, 16, 64);
        cp += __shfl_xor(cp, 32, 64);
        if (l < 16) {
          colS[w][h * 64 + st * 16 + lo] += ce;
          colP[w][h * 64 + st * 16 + lo] += cp;
        }
      }
    }
    if (h == 0) {
      __syncthreads();      // all waves done reading h=0 tile
      STAGE(colBase + 64);  // stage h=1
      __syncthreads();      // drained + visible
    }
  }

  // Row side: rows are wave-exclusive; 16-lane shfl tree -> block partials.
#pragma unroll
  for (int r = 0; r < 4; ++r) {
    float s0 = Sac0[r], p0 = Pac0[r], s1 = Sac1[r], p1 = Pac1[r];
#pragma unroll
    for (int m = 1; m < 16; m <<= 1) {
      s0 += __shfl_xor(s0, m, 64);
      p0 += __shfl_xor(p0, m, 64);
      s1 += __shfl_xor(s1, m, 64);
      p1 += __shfl_xor(p1, m, 64);
    }
    if (lo == 0) {
      const int rl = w * 32 + g * 4 + r;  // local row
      SrowL[rl] = s0;      ProwL[rl] = p0;
      SrowL[rl + 16] = s1; ProwL[rl + 16] = p1;
    }
  }

  __syncthreads();  // SrowL + all waves' colS slices complete

  if (tid < 128) {
    // Row partials -> slab cb (unique writer), 512B coalesced bursts.
    Spart[cb * NN + rb * 128 + tid] = SrowL[tid];
    Ppart[cb * NN + rb * 128 + tid] = ProwL[tid];
    if (!diag) {
      // Col partials -> slab rb (unique writer, rb < cb); col index == tid.
      float S = colS[0][tid] + colS[1][tid] + colS[2][tid] + colS[3][tid];
      float P = colP[0][tid] + colP[1][tid] + colP[2][tid] + colP[3][tid];
      Spart[rb * NN + colBase + tid] = S;
      Ppart[rb * NN + colBase + tid] = P;
    }
  }
#undef STAGE
}

// Kernel 3: gather the 64 partials per row (coalesced), per-row loss, mean.
__global__ void finish_kernel(const float* __restrict__ Spart,
                              const float* __restrict__ Ppart,
                              const int* __restrict__ labels,
                              const int* __restrict__ cnt,
                              float* __restrict__ out) {
  int i = blockIdx.x * 256 + threadIdx.x;  // 8192 threads
  float S = 0.f, P = 0.f;
#pragma unroll 8
  for (int p = 0; p < NB; ++p) {
    S += Spart[p * NN + i];
    P += Ppart[p * NN + i];
  }
  float C = (float)(cnt[labels[i]] - 1);
  float lp = P * INVT - C * (INVT + logf(S + EPSF));
  float v = lp / (C + EPSF);
#pragma unroll
  for (int m = 1; m < 64; m <<= 1) v += __shfl_xor(v, m, 64);
  if ((threadIdx.x & 63) == 0) atomicAdd(out, -v * (1.0f / NN));
}

extern "C" void kernel_launch(void* const* d_in, const int* in_sizes, int n_in,
                              void* d_out, int out_size, void* d_ws, size_t ws_size,
                              hipStream_t stream) {
  const float* feats = (const float*)d_in[0];
  const int* labels = (const int*)d_in[1];

  // ws layout: [0,8MB) bf16 feats; [8,10MB) Spart[64][8192]; [10,12MB) Ppart;
  // then cnt (128 i32). Spart/Ppart need no init (every cell written once).
  unsigned short* fb = (unsigned short*)d_ws;
  const size_t FB_BYTES = (size_t)NN * KK * 2;  // 8388608
  float* Spart = (float*)((char*)d_ws + FB_BYTES);
  float* Ppart = Spart + (size_t)NB * NN;
  int* cnt = (int*)(Ppart + (size_t)NB * NN);

  hipMemsetAsync(cnt, 0, 512, stream);
  hipMemsetAsync(d_out, 0, sizeof(float), stream);

  prep_kernel<<<dim3((NN * KK / 8) / 256), dim3(256), 0, stream>>>(feats, labels, fb, cnt);
  scl_main_kernel<<<dim3(NTRI), dim3(256), 0, stream>>>(fb, labels, Spart, Ppart);
  finish_kernel<<<dim3(NN / 256), dim3(256), 0, stream>>>(Spart, Ppart, labels, cnt, (float*)d_out);
}